// Round 15
// baseline (135.863 us; speedup 1.0000x reference)
//
#include <hip/hip_runtime.h>
#include <hip/hip_bf16.h>
#include <cmath>

typedef __bf16 bf16_t;
typedef __bf16 bf16x8 __attribute__((ext_vector_type(8)));
typedef __bf16 bf16x4 __attribute__((ext_vector_type(4)));
typedef float  f32x4  __attribute__((ext_vector_type(4)));

static constexpr int B_  = 2, S_ = 2048, H_ = 1024, I_ = 2048, NST = 16;
static constexpr int ROWS  = B_ * S_;      // 4096
static constexpr int TWO_I = 2 * I_;       // 4096
static constexpr int XPD   = 2 * NST + 1;  // 33
static constexpr int XPN   = 64;           // padded xproj cols

#define AS_G(p) ((const __attribute__((address_space(1))) void*)(p))
#define AS_L(p) ((__attribute__((address_space(3))) void*)(p))

template<int N> __device__ __forceinline__ void wait_vmcnt();
template<> __device__ __forceinline__ void wait_vmcnt<4>() {
    asm volatile("s_waitcnt vmcnt(4)" ::: "memory");
}

__device__ __forceinline__ float softplus_f(float x) {
    return x > 15.f ? x : log1pf(__expf(x));
}

__device__ __forceinline__ f32x4 b2f(bf16x4 v) {
    return (f32x4){(float)v[0], (float)v[1], (float)v[2], (float)v[3]};
}

__device__ __forceinline__ float fast_exp2(float x) {
#if __has_builtin(__builtin_amdgcn_exp2f)
    return __builtin_amdgcn_exp2f(x);
#else
    return exp2f(x);
#endif
}
__device__ __forceinline__ float fast_rcp(float x) {
#if __has_builtin(__builtin_amdgcn_rcpf)
    return __builtin_amdgcn_rcpf(x);
#else
    return 1.f / x;
#endif
}
__device__ __forceinline__ float fast_sigmoid(float x) {
    return fast_rcp(1.f + __expf(-x));
}
__device__ __forceinline__ float rflf(float x) {
    return __int_as_float(__builtin_amdgcn_readfirstlane(__float_as_int(x)));
}

// XCD supertile swizzle: flat id -> (bx,by); 8 XCDs arranged XW x (8/XW).
template<int GX, int GY, int XW>
__device__ __forceinline__ void xcd_swz(int id, int& bx, int& by) {
    constexpr int SX = GX / XW;
    constexpr int SY = GY * XW / 8;
    const int xcd = id & 7;
    const int j   = id >> 3;
    bx = (xcd % XW) * SX + j % SX;
    by = (xcd / XW) * SY + j / SX;
}

// ---------------- fused prep: cvt x->bf16 | W_in^T | W_out^T | misc ----------------

__global__ __launch_bounds__(256)
void prep_all(const float* __restrict__ x, const float* __restrict__ W_in,
              const float* __restrict__ W_out, const float* __restrict__ A_param,
              const float* __restrict__ Wx, const float* __restrict__ conv_w,
              bf16_t* __restrict__ Xb, bf16_t* __restrict__ W1t,
              bf16_t* __restrict__ Wot, float* __restrict__ A2T,
              float* __restrict__ cwT, bf16_t* __restrict__ WxTb)
{
    const int b   = blockIdx.x;
    const int tid = threadIdx.x;
    __shared__ float t[32][33];

    if (b < 4096) {
        const int i = b * 256 + tid;
        f32x4 v = *(const f32x4*)(x + (size_t)i * 4);
        bf16x4 o;
        o[0] = (bf16_t)v[0]; o[1] = (bf16_t)v[1];
        o[2] = (bf16_t)v[2]; o[3] = (bf16_t)v[3];
        *(bf16x4*)(Xb + (size_t)i * 4) = o;
    } else if (b < 8192) {
        const int tb = b - 4096;
        const int c0 = (tb & 127) * 32, r0 = (tb >> 7) * 32;
        const int tx = tid & 31, ty = tid >> 5;
        #pragma unroll
        for (int k = 0; k < 4; ++k)
            t[ty + 8 * k][tx] = W_in[(size_t)(r0 + ty + 8 * k) * 4096 + c0 + tx];
        __syncthreads();
        #pragma unroll
        for (int k = 0; k < 4; ++k)
            W1t[(size_t)(c0 + ty + 8 * k) * 1024 + r0 + tx] = (bf16_t)t[tx][ty + 8 * k];
    } else if (b < 10240) {
        const int tb = b - 8192;
        const int c0 = (tb & 31) * 32, r0 = (tb >> 5) * 32;
        const int tx = tid & 31, ty = tid >> 5;
        #pragma unroll
        for (int k = 0; k < 4; ++k)
            t[ty + 8 * k][tx] = W_out[(size_t)(r0 + ty + 8 * k) * 1024 + c0 + tx];
        __syncthreads();
        #pragma unroll
        for (int k = 0; k < 4; ++k)
            Wot[(size_t)(c0 + ty + 8 * k) * 2048 + r0 + tx] = (bf16_t)t[tx][ty + 8 * k];
    } else {
        const int i = (b - 10240) * 256 + tid;
        if (i < NST * I_) {
            int n = i >> 11, c = i & (I_ - 1);
            float sp = softplus_f(A_param[(size_t)c * NST + n]);
            A2T[i] = -fminf(fmaxf(sp, 0.1f), 10.f) * 1.44269504088896340736f;
        }
        if (i < 4 * I_) {
            int j = i >> 11, c = i & (I_ - 1);
            cwT[i] = conv_w[(size_t)c * 4 + j];
        }
        if (i < XPN * I_) {
            int j = i >> 11, c = i & (I_ - 1);
            WxTb[i] = (j < XPD) ? (bf16_t)Wx[(size_t)c * XPD + j] : (bf16_t)0.f;
        }
    }
}

// ---------------- GEMM1: m97 structure — 128^2 tile, single 16 KiB buffer, 2-barrier ----------------
// 4 waves (2x2), per-wave 64x64. Per K-step: global_load_lds -> syncthreads ->
// ds_read frags -> MFMA -> syncthreads. High TLP: LDS 32 KiB total, VGPR ~90 ->
// multiple blocks/CU; inter-block overlap hides the barrier drain (m114 mechanism).

template<int M, int N, int K, int GX, int GY, int XW>
__global__ __launch_bounds__(256)
void gemm1_m97(const bf16_t* __restrict__ A, const bf16_t* __restrict__ Bt,
               bf16_t* __restrict__ C)
{
    constexpr int BM = 128, BN = 128, BK = 32;
    constexpr int NT = K / BK;
    constexpr int MR = 4, NR = 4;

    __shared__ bf16_t lA[BM * BK];
    __shared__ bf16_t lB[BN * BK];

    int bx, by;
    xcd_swz<GX, GY, XW>(blockIdx.x, bx, by);
    const int bm = by * BM;
    const int bn = bx * BN;

    const int tid  = threadIdx.x;
    const int lane = tid & 63;
    const int wave = tid >> 6;
    const int wm   = wave >> 1;
    const int wn   = wave & 1;

    const int frow = lane & 15;
    const int fsw  = ((lane >> 4) ^ ((frow >> 1) & 3)) << 3;

    const int str = tid >> 2;              // 0..63
    const int stp = tid & 3;

    const bf16_t* baseA[2];
    const bf16_t* baseB[2];
    #pragma unroll
    for (int a = 0; a < 2; ++a) {
        const int rt = a * 64 + str;
        const int ksw = (stp ^ ((rt >> 1) & 3)) << 3;
        baseA[a] = A  + (size_t)(bm + rt) * K + ksw;
        baseB[a] = Bt + (size_t)(bn + rt) * K + ksw;
    }

    f32x4 acc[MR][NR];
    #pragma unroll
    for (int m = 0; m < MR; ++m)
        #pragma unroll
        for (int n = 0; n < NR; ++n)
            acc[m][n] = (f32x4){0.f, 0.f, 0.f, 0.f};

    for (int t = 0; t < NT; ++t) {
        const int k0 = t * BK;
        #pragma unroll
        for (int a = 0; a < 2; ++a) {
            __builtin_amdgcn_global_load_lds(AS_G(baseA[a] + k0),
                AS_L(lA + a * 2048 + wave * 512), 16, 0, 0);
            __builtin_amdgcn_global_load_lds(AS_G(baseB[a] + k0),
                AS_L(lB + a * 2048 + wave * 512), 16, 0, 0);
        }
        __syncthreads();

        bf16x8 af[MR], bfr[NR];
        #pragma unroll
        for (int m = 0; m < MR; ++m)
            af[m] = *(const bf16x8*)(lA + (wm * 64 + m * 16 + frow) * 32 + fsw);
        #pragma unroll
        for (int n = 0; n < NR; ++n)
            bfr[n] = *(const bf16x8*)(lB + (wn * 64 + n * 16 + frow) * 32 + fsw);

        #pragma unroll
        for (int m = 0; m < MR; ++m)
            #pragma unroll
            for (int n = 0; n < NR; ++n)
                acc[m][n] = __builtin_amdgcn_mfma_f32_16x16x32_bf16(
                    af[m], bfr[n], acc[m][n], 0, 0, 0);

        __syncthreads();
    }

    const int crow = (lane >> 4) * 4;
    const int ccol = lane & 15;
    #pragma unroll
    for (int m = 0; m < MR; ++m)
        #pragma unroll
        for (int n = 0; n < NR; ++n)
            #pragma unroll
            for (int r = 0; r < 4; ++r)
                C[(size_t)(bm + wm * 64 + m * 16 + crow + r) * N
                  + (bn + wn * 64 + n * 16 + ccol)] = (bf16_t)acc[m][n][r];
}

// ---------------- GEMM3: 128x128 tile, 8 waves in 2 K-groups, in-block split-K ----------------

template<int M, int N, int K, int GX, int GY, int XW>
__global__ __launch_bounds__(512)
void gemm3_kg(const bf16_t* __restrict__ A, const bf16_t* __restrict__ Bt,
              float* __restrict__ C)
{
    constexpr int BM = 128, BN = 128, BK = 32;
    constexpr int KH = K / 2;
    constexpr int NT = KH / BK;
    constexpr int MR = 4, NR = 4, MH = 2;

    __shared__ bf16_t smem[65536];

    int bx, by;
    xcd_swz<GX, GY, XW>(blockIdx.x, bx, by);
    const int bm = by * BM;
    const int bn = bx * BN;

    const int tid  = threadIdx.x;
    const int lane = tid & 63;
    const int wave = tid >> 6;
    const int grp  = wave >> 2;
    const int gw   = wave & 3;
    const int wm   = gw >> 1;
    const int wn   = gw & 1;

    const int frow = lane & 15;
    const int fsw  = ((lane >> 4) ^ ((frow >> 1) & 3)) << 3;

    const int gtid = tid & 255;
    const int str  = gtid >> 2;
    const int stp  = gtid & 3;

    bf16_t* lA = smem + grp * 16384;
    bf16_t* lB = smem + 32768 + grp * 16384;

    const bf16_t* baseA[2];
    #pragma unroll
    for (int a = 0; a < 2; ++a) {
        const int rt = a * 64 + str;
        baseA[a] = A + (size_t)(bm + rt) * K + grp * KH + ((stp ^ ((rt >> 1) & 3)) << 3);
    }
    const bf16_t* baseB[2];
    #pragma unroll
    for (int a = 0; a < 2; ++a) {
        const int rt = a * 64 + str;
        baseB[a] = Bt + (size_t)(bn + rt) * K + grp * KH + ((stp ^ ((rt >> 1) & 3)) << 3);
    }

    f32x4 acc[MR][NR];
    #pragma unroll
    for (int m = 0; m < MR; ++m)
        #pragma unroll
        for (int n = 0; n < NR; ++n)
            acc[m][n] = (f32x4){0.f, 0.f, 0.f, 0.f};

    auto stageA = [&](int k0, int b) {
        #pragma unroll
        for (int a = 0; a < 2; ++a)
            __builtin_amdgcn_global_load_lds(AS_G(baseA[a] + k0),
                AS_L(lA + b * 4096 + a * 2048 + gw * 512), 16, 0, 0);
    };
    auto stageB = [&](int k0, int b) {
        #pragma unroll
        for (int a = 0; a < 2; ++a)
            __builtin_amdgcn_global_load_lds(AS_G(baseB[a] + k0),
                AS_L(lB + b * 4096 + a * 2048 + gw * 512), 16, 0, 0);
    };

    stageA(0, 0); stageB(0, 0);
    stageA(BK, 1); stageB(BK, 1);
    wait_vmcnt<4>();
    __builtin_amdgcn_s_barrier();

    #pragma unroll 1
    for (int t = 0; t < NT; ++t) {
        const int buf = t & 3;
        const int nb  = (t + 2) & 3;
        int kn = (t + 2) * BK;
        if (kn >= KH) kn -= KH;

        bf16x8 bfr[NR];
        #pragma unroll
        for (int n = 0; n < NR; ++n)
            bfr[n] = *(const bf16x8*)(lB + buf * 4096 + (wn * 64 + n * 16 + frow) * 32 + fsw);
        bf16x8 af0[MH];
        #pragma unroll
        for (int m = 0; m < MH; ++m)
            af0[m] = *(const bf16x8*)(lA + buf * 4096 + (wm * 64 + m * 16 + frow) * 32 + fsw);
        stageA(kn, nb);

        __builtin_amdgcn_s_setprio(1);
        #pragma unroll
        for (int m = 0; m < MH; ++m)
            #pragma unroll
            for (int n = 0; n < NR; ++n)
                acc[m][n] = __builtin_amdgcn_mfma_f32_16x16x32_bf16(
                    af0[m], bfr[n], acc[m][n], 0, 0, 0);
        __builtin_amdgcn_s_setprio(0);

        bf16x8 af1[MR - MH];
        #pragma unroll
        for (int m = 0; m < MR - MH; ++m)
            af1[m] = *(const bf16x8*)(lA + buf * 4096 + (wm * 64 + (MH + m) * 16 + frow) * 32 + fsw);
        stageB(kn, nb);

        __builtin_amdgcn_s_setprio(1);
        #pragma unroll
        for (int m = 0; m < MR - MH; ++m)
            #pragma unroll
            for (int n = 0; n < NR; ++n)
                acc[MH + m][n] = __builtin_amdgcn_mfma_f32_16x16x32_bf16(
                    af1[m], bfr[n], acc[MH + m][n], 0, 0, 0);
        __builtin_amdgcn_s_setprio(0);

        wait_vmcnt<4>();
        __builtin_amdgcn_s_barrier();
    }

    asm volatile("s_waitcnt vmcnt(0)" ::: "memory");
    __builtin_amdgcn_s_barrier();

    float* accx = (float*)smem;
    const int crow = (lane >> 4) * 4;
    const int ccol = lane & 15;

    if (grp == 1) {
        #pragma unroll
        for (int m = 0; m < MR; ++m)
            #pragma unroll
            for (int n = 0; n < NR; ++n) {
                const int row = wm * 64 + m * 16 + crow;
                const int col = wn * 64 + n * 16 + ccol;
                #pragma unroll
                for (int r = 0; r < 4; ++r)
                    accx[(size_t)(row + r) * 132 + col] = acc[m][n][r];
            }
    }
    __syncthreads();
    if (grp == 0) {
        #pragma unroll
        for (int m = 0; m < MR; ++m)
            #pragma unroll
            for (int n = 0; n < NR; ++n) {
                const int row = wm * 64 + m * 16 + crow;
                const int col = wn * 64 + n * 16 + ccol;
                #pragma unroll
                for (int r = 0; r < 4; ++r)
                    C[(size_t)(bm + row + r) * N + bn + col] =
                        acc[m][n][r] + accx[(size_t)(row + r) * 132 + col];
            }
    }
}

// ---------------- conv + silu + layernorm -> Xn (bf16) ----------------

__global__ __launch_bounds__(256)
void conv_ln(const bf16_t* __restrict__ xz,
             const float* __restrict__ cwT,
             const float* __restrict__ ln_g,
             const float* __restrict__ ln_b,
             bf16_t* __restrict__ Xn)
{
    const int row  = blockIdx.x;
    const int s    = row & (S_ - 1);
    const int tid  = threadIdx.x;
    const int lane = tid & 63;
    const int wave = tid >> 6;
    const bf16_t* xzr = xz + (size_t)row * TWO_I;

    __shared__ float lnr[4][2];

    float xc[8];
    float sm = 0.f, sq = 0.f;

    #pragma unroll
    for (int g = 0; g < 2; ++g) {
        const int c = g * 1024 + tid * 4;
        const f32x4 w0 = *(const f32x4*)(cwT + 0 * I_ + c);
        const f32x4 w1 = *(const f32x4*)(cwT + 1 * I_ + c);
        const f32x4 w2 = *(const f32x4*)(cwT + 2 * I_ + c);
        const f32x4 w3 = *(const f32x4*)(cwT + 3 * I_ + c);
        const f32x4 z4 = (f32x4){0.f, 0.f, 0.f, 0.f};
        const f32x4 xv0 = (s >= 3) ? b2f(*(const bf16x4*)(xzr - 3 * TWO_I + c)) : z4;
        const f32x4 xv1 = (s >= 2) ? b2f(*(const bf16x4*)(xzr - 2 * TWO_I + c)) : z4;
        const f32x4 xv2 = (s >= 1) ? b2f(*(const bf16x4*)(xzr - 1 * TWO_I + c)) : z4;
        const f32x4 xv3 = b2f(*(const bf16x4*)(xzr + c));
        const f32x4 a = w0 * xv0 + w1 * xv1 + w2 * xv2 + w3 * xv3;
        #pragma unroll
        for (int e = 0; e < 4; ++e) {
            const float v = a[e];
            const float t = v * fast_sigmoid(v);
            xc[g * 4 + e] = t;
            sm += t; sq += t * t;
        }
    }

    #pragma unroll
    for (int off = 32; off; off >>= 1) {
        sm += __shfl_xor(sm, off, 64);
        sq += __shfl_xor(sq, off, 64);
    }
    if (lane == 0) { lnr[wave][0] = sm; lnr[wave][1] = sq; }
    __syncthreads();
    sm = lnr[0][0] + lnr[1][0] + lnr[2][0] + lnr[3][0];
    sq = lnr[0][1] + lnr[1][1] + lnr[2][1] + lnr[3][1];
    const float mu = sm * (1.f / I_);
    const float rs = rsqrtf(sq * (1.f / I_) - mu * mu + 1e-5f);

    #pragma unroll
    for (int g = 0; g < 2; ++g) {
        const int c = g * 1024 + tid * 4;
        const f32x4 gg = *(const f32x4*)(ln_g + c);
        const f32x4 bb = *(const f32x4*)(ln_b + c);
        bf16x4 h4;
        #pragma unroll
        for (int e = 0; e < 4; ++e)
            h4[e] = (bf16_t)((xc[g * 4 + e] - mu) * rs * gg[e] + bb[e]);
        *(bf16x4*)(Xn + (size_t)row * I_ + c) = h4;
    }
}

// ---------------- xproj GEMM: xp_part[ks][ROWS][64] = Xn @ WxTb^T ----------------

__global__ __launch_bounds__(256)
void xproj_gemm(const bf16_t* __restrict__ Xn,
                const bf16_t* __restrict__ Wb, float* __restrict__ xp_part)
{
    constexpr int BM = 128, BK = 32, KS = 512;
    __shared__ bf16_t lA[BM * BK];
    __shared__ bf16_t lB[XPN * BK];

    const int bm   = blockIdx.x * BM;
    const int ks   = blockIdx.y;
    const int tid  = threadIdx.x;
    const int lane = tid & 63;
    const int wave = tid >> 6;
    const int wm   = (wave >> 1) * 64;
    const int wn   = (wave & 1) * 32;

    const int srow  = lane >> 2;
    const int skoff = (lane & 3) * 8;
    const int frow  = lane & 15;
    const int fko   = (lane >> 4) * 8;

    f32x4 acc[4][2];
    #pragma unroll
    for (int m = 0; m < 4; ++m)
        #pragma unroll
        for (int n = 0; n < 2; ++n)
            acc[m][n] = (f32x4){0.f, 0.f, 0.f, 0.f};

    for (int k0 = ks * KS; k0 < ks * KS + KS; k0 += BK) {
        #pragma unroll
        for (int t = 0; t < 2; ++t) {
            const int c = wave * 2 + t;
            const bf16_t* ga = Xn + (size_t)(bm + c * 16 + srow) * I_ + k0 + skoff;
            __builtin_amdgcn_global_load_lds(AS_G(ga), AS_L(lA + c * 512), 16, 0, 0);
        }
        const bf16_t* gb = Wb + (size_t)(wave * 16 + srow) * I_ + k0 + skoff;
        __builtin_amdgcn_global_load_lds(AS_G(gb), AS_L(lB + wave * 512), 16, 0, 0);
        __syncthreads();

        bf16x8 af[4], bf2[2];
        #pragma unroll
        for (int m = 0; m < 4; ++m)
            af[m] = *(const bf16x8*)(lA + (wm + m * 16 + frow) * BK + fko);
        #pragma unroll
        for (int n = 0; n < 2; ++n)
            bf2[n] = *(const bf16x8*)(lB + (wn + n * 16 + frow) * BK + fko);

        #pragma unroll
        for (int m = 0; m < 4; ++m)
            #pragma unroll
            for (int n = 0; n < 2; ++n)
                acc[m][n] = __builtin_amdgcn_mfma_f32_16x16x32_bf16(
                    af[m], bf2[n], acc[m][n], 0, 0, 0);

        __syncthreads();
    }

    float* out = xp_part + ((size_t)ks * ROWS + bm) * XPN;
    const int crow = (lane >> 4) * 4;
    const int ccol = lane & 15;
    #pragma unroll
    for (int m = 0; m < 4; ++m)
        #pragma unroll
        for (int n = 0; n < 2; ++n)
            #pragma unroll
            for (int r = 0; r < 4; ++r)
                out[(size_t)(wm + m * 16 + crow + r) * XPN
                    + (wn + n * 16 + ccol)] = acc[m][n][r];
}

// ---------------- SSM pointwise + gate -> U (bf16); 2 rows per block ----------------

__global__ __launch_bounds__(256)
void ssm_gate(const bf16_t* __restrict__ xz,
              const bf16_t* __restrict__ Xn,
              const float* __restrict__ xp_part,
              const float* __restrict__ A2T,
              const float* __restrict__ Dv,
              bf16_t* __restrict__ U)
{
    const int row0 = blockIdx.x * 2;
    const int tid  = threadIdx.x;

    __shared__ float xps[2][XPD];
    __shared__ float bcs[2][NST];

    if (tid < XPD) {
        float s = 0.f;
        #pragma unroll
        for (int ks = 0; ks < 4; ++ks)
            s += xp_part[((size_t)ks * ROWS + row0) * XPN + tid];
        xps[0][tid] = s;
    } else if (tid >= 64 && tid < 64 + XPD) {
        const int j = tid - 64;
        float s = 0.f;
        #pragma unroll
        for (int ks = 0; ks < 4; ++ks)
            s += xp_part[((size_t)ks * ROWS + row0 + 1) * XPN + j];
        xps[1][j] = s;
    }
    __syncthreads();
    if (tid < NST)
        bcs[0][tid] = xps[0][1 + tid] * xps[0][1 + NST + tid];
    else if (tid >= 64 && tid < 64 + NST) {
        const int n = tid - 64;
        bcs[1][n] = xps[1][1 + n] * xps[1][1 + NST + n];
    }
    __syncthreads();

    const float d0 = fminf(fmaxf(softplus_f(xps[0][0]), 1e-6f), 10.f);
    const float d1 = fminf(fmaxf(softplus_f(xps[1][0]), 1e-6f), 10.f);

    const bf16_t* z0 = xz + (size_t)row0 * TWO_I + I_;
    const bf16_t* z1 = z0 + TWO_I;
    bf16_t* u0 = U + (size_t)row0 * I_;
    bf16_t* u1 = u0 + I_;

    #pragma unroll 1
    for (int g = 0; g < 2; ++g) {
        const int c = g * 1024 + tid * 4;
        f32x4 sa0 = (f32x4){0.f, 0.f, 0.f, 0.f};
        f32x4 sa1 = (f32x4){0.f, 0.f, 0.f, 0.f};
        #pragma unroll 1
        for (int nb = 0; nb < 4; ++nb) {
            const float* ap = A2T + (size_t)(nb * 4) * I_ + c;
            const f32x4 a0 = *(const f32x4*)(ap);
            const f32x4 a1 = *(const f32x4*)(ap + I_);
            const f32x4 a2 = *(const f32x4*)(ap + 2 * I_);
            const f32x4 a3 = *(const f32x4*)(ap + 3 * I_);
            const float b00 = rflf(bcs[0][nb * 4 + 0]), b10 = rflf(bcs[1][nb * 4 + 0]);
            const float b01 = rflf(bcs[0][nb * 4 + 1]), b11 = rflf(bcs[1][nb * 4 + 1]);
            const float b02 = rflf(bcs[0][nb * 4 + 2]), b12 = rflf(bcs[1][nb * 4 + 2]);
            const float b03 = rflf(bcs[0][nb * 4 + 3]), b13 = rflf(bcs[1][nb * 4 + 3]);
            #pragma unroll
            for (int e = 0; e < 4; ++e) {
                sa0[e] += b00 * fast_exp2(d0 * a0[e]);
                sa1[e] += b10 * fast_exp2(d1 * a0[e]);
                sa0[e] += b01 * fast_exp2(d0 * a1[e]);
                sa1[e] += b11 * fast_exp2(d1 * a1[e]);
                sa0[e] += b02 * fast_exp2(d0 * a2[e]);
                sa1[e] += b12 * fast_exp2(d1 * a2[e]);
                sa0[e] += b03 * fast_exp2(d0 * a3[e]);
                sa1[e] += b13 * fast_exp2(d1 * a3[e]);
            }
        }
        const f32x4 dvv = *(const f32x4*)(Dv + c);
        const f32x4 xn0 = b2f(*(const bf16x4*)(Xn + (size_t)row0 * I_ + c));
        const f32x4 xn1 = b2f(*(const bf16x4*)(Xn + (size_t)(row0 + 1) * I_ + c));
        const f32x4 zv0 = b2f(*(const bf16x4*)(z0 + c));
        const f32x4 zv1 = b2f(*(const bf16x4*)(z1 + c));
        bf16x4 o0, o1;
        #pragma unroll
        for (int e = 0; e < 4; ++e) {
            const float y0 = xn0[e] * (sa0[e] + dvv[e]);
            const float y1 = xn1[e] * (sa1[e] + dvv[e]);
            const float zz0 = zv0[e], zz1 = zv1[e];
            o0[e] = (bf16_t)(y0 * zz0 * fast_sigmoid(zz0));
            o1[e] = (bf16_t)(y1 * zz1 * fast_sigmoid(zz1));
        }
        *(bf16x4*)(u0 + c) = o0;
        *(bf16x4*)(u1 + c) = o1;
    }
}

// ---------------- launch ----------------

extern "C" void kernel_launch(void* const* d_in, const int* in_sizes, int n_in,
                              void* d_out, int out_size, void* d_ws, size_t ws_size,
                              hipStream_t stream)
{
    const float* x     = (const float*)d_in[0];
    const float* W_in  = (const float*)d_in[1];
    const float* convw = (const float*)d_in[2];
    const float* ln_g  = (const float*)d_in[3];
    const float* ln_b  = (const float*)d_in[4];
    const float* Wx    = (const float*)d_in[5];
    const float* A_p   = (const float*)d_in[6];
    const float* Dv    = (const float*)d_in[7];
    const float* W_out = (const float*)d_in[8];
    float* out = (float*)d_out;

    char* ws = (char*)d_ws;
    bf16_t* Xb   = (bf16_t*)(ws);                                // 8 MiB (dead after GEMM1)
    bf16_t* W1t  = (bf16_t*)(ws + (size_t)(8u  << 20));          // 8 MiB (dead after GEMM1)
    bf16_t* Wot  = (bf16_t*)(ws + (size_t)(16u << 20));          // 4 MiB
    float*  A2T  = (float*) (ws + (size_t)(20u << 20));          // 128 KiB
    float*  cwT  = (float*) (ws + (size_t)(20u << 20) + (128u << 10)); // 32 KiB
    bf16_t* WxTb = (bf16_t*)(ws + (size_t)(20u << 20) + (256u << 10)); // 256 KiB
    bf16_t* XZb  = (bf16_t*)(ws + (size_t)(22u << 20));          // 32 MiB [4096][4096]
    bf16_t* U    = (bf16_t*)(ws + (size_t)(54u << 20));          // 16 MiB
    bf16_t* Xn   = (bf16_t*)(ws);                                // 16 MiB (reuses Xb+W1t)
    float*  xp4  = (float*) (ws + (size_t)(86u << 20));          // 4 MiB [4][4096][64]

    prep_all<<<10752, 256, 0, stream>>>(x, W_in, W_out, A_p, Wx, convw,
                                        Xb, W1t, Wot, A2T, cwT, WxTb);

    // GEMM1: m97 single-buffer 128^2, grid 1024 (32x32, XCD 4-wide supertiles)
    gemm1_m97<ROWS, TWO_I, H_, 32, 32, 4>
        <<<1024, 256, 0, stream>>>(Xb, W1t, XZb);
    conv_ln<<<ROWS, 256, 0, stream>>>(XZb, cwT, ln_g, ln_b, Xn);
    xproj_gemm<<<dim3(ROWS / 128, 4), 256, 0, stream>>>(Xn, WxTb, xp4);
    ssm_gate<<<ROWS / 2, 256, 0, stream>>>(XZb, Xn, xp4, A2T, Dv, U);
    // GEMM3: 128^2 tile, 8 waves / 2 K-groups, grid 256 (8x32, XCD 2x4 supertiles)
    gemm3_kg<ROWS, H_, I_, 8, 32, 2>
        <<<256, 512, 0, stream>>>(U, Wot, out);
}

// Round 16
// 119.340 us; speedup vs baseline: 1.1385x; 1.1385x over previous
//
#include <hip/hip_runtime.h>
#include <hip/hip_bf16.h>
#include <cmath>

typedef __bf16 bf16_t;
typedef __bf16 bf16x8 __attribute__((ext_vector_type(8)));
typedef __bf16 bf16x4 __attribute__((ext_vector_type(4)));
typedef float  f32x4  __attribute__((ext_vector_type(4)));

static constexpr int B_  = 2, S_ = 2048, H_ = 1024, I_ = 2048, NST = 16;
static constexpr int ROWS  = B_ * S_;      // 4096
static constexpr int TWO_I = 2 * I_;       // 4096
static constexpr int XPD   = 2 * NST + 1;  // 33
static constexpr int XPN   = 64;           // padded xproj cols

#define AS_G(p) ((const __attribute__((address_space(1))) void*)(p))
#define AS_L(p) ((__attribute__((address_space(3))) void*)(p))

template<int N> __device__ __forceinline__ void wait_vmcnt();
template<> __device__ __forceinline__ void wait_vmcnt<4>() {
    asm volatile("s_waitcnt vmcnt(4)" ::: "memory");
}

__device__ __forceinline__ float softplus_f(float x) {
    return x > 15.f ? x : log1pf(__expf(x));
}

__device__ __forceinline__ f32x4 b2f(bf16x4 v) {
    return (f32x4){(float)v[0], (float)v[1], (float)v[2], (float)v[3]};
}

__device__ __forceinline__ float fast_exp2(float x) {
#if __has_builtin(__builtin_amdgcn_exp2f)
    return __builtin_amdgcn_exp2f(x);
#else
    return exp2f(x);
#endif
}
__device__ __forceinline__ float fast_rcp(float x) {
#if __has_builtin(__builtin_amdgcn_rcpf)
    return __builtin_amdgcn_rcpf(x);
#else
    return 1.f / x;
#endif
}
__device__ __forceinline__ float fast_sigmoid(float x) {
    return fast_rcp(1.f + __expf(-x));
}
__device__ __forceinline__ float rflf(float x) {
    return __int_as_float(__builtin_amdgcn_readfirstlane(__float_as_int(x)));
}

// XCD supertile swizzle: flat id -> (bx,by); 8 XCDs arranged XW x (8/XW).
template<int GX, int GY, int XW>
__device__ __forceinline__ void xcd_swz(int id, int& bx, int& by) {
    constexpr int SX = GX / XW;
    constexpr int SY = GY * XW / 8;
    const int xcd = id & 7;
    const int j   = id >> 3;
    bx = (xcd % XW) * SX + j % SX;
    by = (xcd / XW) * SY + j / SX;
}

// ---------------- fused prep: cvt x->bf16 | W_in^T | W_out^T | misc ----------------

__global__ __launch_bounds__(256)
void prep_all(const float* __restrict__ x, const float* __restrict__ W_in,
              const float* __restrict__ W_out, const float* __restrict__ A_param,
              const float* __restrict__ Wx, const float* __restrict__ conv_w,
              bf16_t* __restrict__ Xb, bf16_t* __restrict__ W1t,
              bf16_t* __restrict__ Wot, float* __restrict__ A2T,
              float* __restrict__ cwT, bf16_t* __restrict__ WxTb)
{
    const int b   = blockIdx.x;
    const int tid = threadIdx.x;
    __shared__ float t[32][33];

    if (b < 4096) {
        const int i = b * 256 + tid;
        f32x4 v = *(const f32x4*)(x + (size_t)i * 4);
        bf16x4 o;
        o[0] = (bf16_t)v[0]; o[1] = (bf16_t)v[1];
        o[2] = (bf16_t)v[2]; o[3] = (bf16_t)v[3];
        *(bf16x4*)(Xb + (size_t)i * 4) = o;
    } else if (b < 8192) {
        const int tb = b - 4096;
        const int c0 = (tb & 127) * 32, r0 = (tb >> 7) * 32;
        const int tx = tid & 31, ty = tid >> 5;
        #pragma unroll
        for (int k = 0; k < 4; ++k)
            t[ty + 8 * k][tx] = W_in[(size_t)(r0 + ty + 8 * k) * 4096 + c0 + tx];
        __syncthreads();
        #pragma unroll
        for (int k = 0; k < 4; ++k)
            W1t[(size_t)(c0 + ty + 8 * k) * 1024 + r0 + tx] = (bf16_t)t[tx][ty + 8 * k];
    } else if (b < 10240) {
        const int tb = b - 8192;
        const int c0 = (tb & 31) * 32, r0 = (tb >> 5) * 32;
        const int tx = tid & 31, ty = tid >> 5;
        #pragma unroll
        for (int k = 0; k < 4; ++k)
            t[ty + 8 * k][tx] = W_out[(size_t)(r0 + ty + 8 * k) * 1024 + c0 + tx];
        __syncthreads();
        #pragma unroll
        for (int k = 0; k < 4; ++k)
            Wot[(size_t)(c0 + ty + 8 * k) * 2048 + r0 + tx] = (bf16_t)t[tx][ty + 8 * k];
    } else {
        const int i = (b - 10240) * 256 + tid;
        if (i < NST * I_) {
            int n = i >> 11, c = i & (I_ - 1);
            float sp = softplus_f(A_param[(size_t)c * NST + n]);
            A2T[i] = -fminf(fmaxf(sp, 0.1f), 10.f) * 1.44269504088896340736f;
        }
        if (i < 4 * I_) {
            int j = i >> 11, c = i & (I_ - 1);
            cwT[i] = conv_w[(size_t)c * 4 + j];
        }
        if (i < XPN * I_) {
            int j = i >> 11, c = i & (I_ - 1);
            WxTb[i] = (j < XPD) ? (bf16_t)Wx[(size_t)c * XPD + j] : (bf16_t)0.f;
        }
    }
}

// ---------------- pipelined GEMM (R11): BK=32, 4 buf, dist-2, 2-phase ----------------

template<int M, int N, int K, int BM, int BN, int WM, int WN, int THREADS,
         int GX, int GY, int XW, typename OutT>
__global__ __launch_bounds__(THREADS)
void gemm_fp(const bf16_t* __restrict__ A, const bf16_t* __restrict__ Bt,
             OutT* __restrict__ C)
{
    constexpr int BK  = 32;
    constexpr int NT  = K / BK;
    constexpr int MR  = BM / WM / 16;
    constexpr int NR  = BN / WN / 16;
    constexpr int MH  = MR / 2;
    constexpr int RPC = THREADS / 4;
    constexpr int CA  = BM / RPC;
    constexpr int CB  = BN / RPC;
    static_assert(CA + CB == 4, "vmcnt template fixed at 4");

    __shared__ bf16_t lA[4][BM * BK];
    __shared__ bf16_t lB[4][BN * BK];

    int bx, by;
    xcd_swz<GX, GY, XW>(blockIdx.x, bx, by);
    const int bm = by * BM;
    const int bn = bx * BN;

    const int tid  = threadIdx.x;
    const int lane = tid & 63;
    const int wave = tid >> 6;
    const int wm   = wave / WN;
    const int wn   = wave % WN;

    const int frow = lane & 15;
    const int fsw  = ((lane >> 4) ^ ((frow >> 1) & 3)) << 3;

    const int str = tid >> 2;
    const int stp = tid & 3;

    const bf16_t* baseA[CA];
    #pragma unroll
    for (int a = 0; a < CA; ++a) {
        const int rt = a * RPC + str;
        baseA[a] = A + (size_t)(bm + rt) * K + ((stp ^ ((rt >> 1) & 3)) << 3);
    }
    const bf16_t* baseB[CB];
    #pragma unroll
    for (int a = 0; a < CB; ++a) {
        const int rt = a * RPC + str;
        baseB[a] = Bt + (size_t)(bn + rt) * K + ((stp ^ ((rt >> 1) & 3)) << 3);
    }

    f32x4 acc[MR][NR];
    #pragma unroll
    for (int m = 0; m < MR; ++m)
        #pragma unroll
        for (int n = 0; n < NR; ++n)
            acc[m][n] = (f32x4){0.f, 0.f, 0.f, 0.f};

    auto stageA = [&](int k0, int b) {
        #pragma unroll
        for (int a = 0; a < CA; ++a)
            __builtin_amdgcn_global_load_lds(AS_G(baseA[a] + k0),
                AS_L(&lA[b][a * RPC * 32 + wave * 512]), 16, 0, 0);
    };
    auto stageB = [&](int k0, int b) {
        #pragma unroll
        for (int a = 0; a < CB; ++a)
            __builtin_amdgcn_global_load_lds(AS_G(baseB[a] + k0),
                AS_L(&lB[b][a * RPC * 32 + wave * 512]), 16, 0, 0);
    };

    stageA(0, 0); stageB(0, 0);
    stageA(BK, 1); stageB(BK, 1);
    wait_vmcnt<4>();
    __builtin_amdgcn_s_barrier();

    #pragma unroll 1
    for (int t = 0; t < NT; ++t) {
        const int buf = t & 3;
        const int nb  = (t + 2) & 3;
        int kn = (t + 2) * BK;
        if (kn >= K) kn -= K;            // wrap: constant in-flight count

        bf16x8 bfr[NR];
        #pragma unroll
        for (int n = 0; n < NR; ++n)
            bfr[n] = *(const bf16x8*)(&lB[buf][(wn * (NR * 16) + n * 16 + frow) * 32 + fsw]);
        bf16x8 af0[MH];
        #pragma unroll
        for (int m = 0; m < MH; ++m)
            af0[m] = *(const bf16x8*)(&lA[buf][(wm * (MR * 16) + m * 16 + frow) * 32 + fsw]);
        stageA(kn, nb);

        __builtin_amdgcn_s_setprio(1);
        #pragma unroll
        for (int m = 0; m < MH; ++m)
            #pragma unroll
            for (int n = 0; n < NR; ++n)
                acc[m][n] = __builtin_amdgcn_mfma_f32_16x16x32_bf16(
                    af0[m], bfr[n], acc[m][n], 0, 0, 0);
        __builtin_amdgcn_s_setprio(0);

        bf16x8 af1[MR - MH];
        #pragma unroll
        for (int m = 0; m < MR - MH; ++m)
            af1[m] = *(const bf16x8*)(&lA[buf][(wm * (MR * 16) + (MH + m) * 16 + frow) * 32 + fsw]);
        stageB(kn, nb);

        __builtin_amdgcn_s_setprio(1);
        #pragma unroll
        for (int m = 0; m < MR - MH; ++m)
            #pragma unroll
            for (int n = 0; n < NR; ++n)
                acc[MH + m][n] = __builtin_amdgcn_mfma_f32_16x16x32_bf16(
                    af1[m], bfr[n], acc[MH + m][n], 0, 0, 0);
        __builtin_amdgcn_s_setprio(0);

        wait_vmcnt<4>();
        __builtin_amdgcn_s_barrier();
    }

    const int crow = (lane >> 4) * 4;
    const int ccol = lane & 15;
    #pragma unroll
    for (int m = 0; m < MR; ++m)
        #pragma unroll
        for (int n = 0; n < NR; ++n)
            #pragma unroll
            for (int r = 0; r < 4; ++r)
                C[(size_t)(bm + wm * (MR * 16) + m * 16 + crow + r) * N
                  + (bn + wn * (NR * 16) + n * 16 + ccol)] = (OutT)acc[m][n][r];
}

// ---------------- GEMM3: 128x128 tile, 8 waves in 2 K-groups, in-block split-K ----------------

template<int M, int N, int K, int GX, int GY, int XW>
__global__ __launch_bounds__(512)
void gemm3_kg(const bf16_t* __restrict__ A, const bf16_t* __restrict__ Bt,
              float* __restrict__ C)
{
    constexpr int BM = 128, BN = 128, BK = 32;
    constexpr int KH = K / 2;
    constexpr int NT = KH / BK;
    constexpr int MR = 4, NR = 4, MH = 2;

    __shared__ bf16_t smem[65536];

    int bx, by;
    xcd_swz<GX, GY, XW>(blockIdx.x, bx, by);
    const int bm = by * BM;
    const int bn = bx * BN;

    const int tid  = threadIdx.x;
    const int lane = tid & 63;
    const int wave = tid >> 6;
    const int grp  = wave >> 2;
    const int gw   = wave & 3;
    const int wm   = gw >> 1;
    const int wn   = gw & 1;

    const int frow = lane & 15;
    const int fsw  = ((lane >> 4) ^ ((frow >> 1) & 3)) << 3;

    const int gtid = tid & 255;
    const int str  = gtid >> 2;
    const int stp  = gtid & 3;

    bf16_t* lA = smem + grp * 16384;
    bf16_t* lB = smem + 32768 + grp * 16384;

    const bf16_t* baseA[2];
    #pragma unroll
    for (int a = 0; a < 2; ++a) {
        const int rt = a * 64 + str;
        baseA[a] = A + (size_t)(bm + rt) * K + grp * KH + ((stp ^ ((rt >> 1) & 3)) << 3);
    }
    const bf16_t* baseB[2];
    #pragma unroll
    for (int a = 0; a < 2; ++a) {
        const int rt = a * 64 + str;
        baseB[a] = Bt + (size_t)(bn + rt) * K + grp * KH + ((stp ^ ((rt >> 1) & 3)) << 3);
    }

    f32x4 acc[MR][NR];
    #pragma unroll
    for (int m = 0; m < MR; ++m)
        #pragma unroll
        for (int n = 0; n < NR; ++n)
            acc[m][n] = (f32x4){0.f, 0.f, 0.f, 0.f};

    auto stageA = [&](int k0, int b) {
        #pragma unroll
        for (int a = 0; a < 2; ++a)
            __builtin_amdgcn_global_load_lds(AS_G(baseA[a] + k0),
                AS_L(lA + b * 4096 + a * 2048 + gw * 512), 16, 0, 0);
    };
    auto stageB = [&](int k0, int b) {
        #pragma unroll
        for (int a = 0; a < 2; ++a)
            __builtin_amdgcn_global_load_lds(AS_G(baseB[a] + k0),
                AS_L(lB + b * 4096 + a * 2048 + gw * 512), 16, 0, 0);
    };

    stageA(0, 0); stageB(0, 0);
    stageA(BK, 1); stageB(BK, 1);
    wait_vmcnt<4>();
    __builtin_amdgcn_s_barrier();

    #pragma unroll 1
    for (int t = 0; t < NT; ++t) {
        const int buf = t & 3;
        const int nb  = (t + 2) & 3;
        int kn = (t + 2) * BK;
        if (kn >= KH) kn -= KH;

        bf16x8 bfr[NR];
        #pragma unroll
        for (int n = 0; n < NR; ++n)
            bfr[n] = *(const bf16x8*)(lB + buf * 4096 + (wn * 64 + n * 16 + frow) * 32 + fsw);
        bf16x8 af0[MH];
        #pragma unroll
        for (int m = 0; m < MH; ++m)
            af0[m] = *(const bf16x8*)(lA + buf * 4096 + (wm * 64 + m * 16 + frow) * 32 + fsw);
        stageA(kn, nb);

        __builtin_amdgcn_s_setprio(1);
        #pragma unroll
        for (int m = 0; m < MH; ++m)
            #pragma unroll
            for (int n = 0; n < NR; ++n)
                acc[m][n] = __builtin_amdgcn_mfma_f32_16x16x32_bf16(
                    af0[m], bfr[n], acc[m][n], 0, 0, 0);
        __builtin_amdgcn_s_setprio(0);

        bf16x8 af1[MR - MH];
        #pragma unroll
        for (int m = 0; m < MR - MH; ++m)
            af1[m] = *(const bf16x8*)(lA + buf * 4096 + (wm * 64 + (MH + m) * 16 + frow) * 32 + fsw);
        stageB(kn, nb);

        __builtin_amdgcn_s_setprio(1);
        #pragma unroll
        for (int m = 0; m < MR - MH; ++m)
            #pragma unroll
            for (int n = 0; n < NR; ++n)
                acc[MH + m][n] = __builtin_amdgcn_mfma_f32_16x16x32_bf16(
                    af1[m], bfr[n], acc[MH + m][n], 0, 0, 0);
        __builtin_amdgcn_s_setprio(0);

        wait_vmcnt<4>();
        __builtin_amdgcn_s_barrier();
    }

    asm volatile("s_waitcnt vmcnt(0)" ::: "memory");
    __builtin_amdgcn_s_barrier();

    float* accx = (float*)smem;
    const int crow = (lane >> 4) * 4;
    const int ccol = lane & 15;

    if (grp == 1) {
        #pragma unroll
        for (int m = 0; m < MR; ++m)
            #pragma unroll
            for (int n = 0; n < NR; ++n) {
                const int row = wm * 64 + m * 16 + crow;
                const int col = wn * 64 + n * 16 + ccol;
                #pragma unroll
                for (int r = 0; r < 4; ++r)
                    accx[(size_t)(row + r) * 132 + col] = acc[m][n][r];
            }
    }
    __syncthreads();
    if (grp == 0) {
        #pragma unroll
        for (int m = 0; m < MR; ++m)
            #pragma unroll
            for (int n = 0; n < NR; ++n) {
                const int row = wm * 64 + m * 16 + crow;
                const int col = wn * 64 + n * 16 + ccol;
                #pragma unroll
                for (int r = 0; r < 4; ++r)
                    C[(size_t)(bm + row + r) * N + bn + col] =
                        acc[m][n][r] + accx[(size_t)(row + r) * 132 + col];
            }
    }
}

// ---------------- conv + silu + layernorm -> Xn (bf16); 4 rows/block ----------------
// Block handles rows row0..row0+3 (same sequence: S_ % 4 == 0). Reads 7 xz rows
// instead of 16 (4x1-row blocks) -> ~2.3x less HBM read on the conv input.

__global__ __launch_bounds__(256)
void conv_ln4(const bf16_t* __restrict__ xz,
              const float* __restrict__ cwT,
              const float* __restrict__ ln_g,
              const float* __restrict__ ln_b,
              bf16_t* __restrict__ Xn)
{
    const int row0 = blockIdx.x * 4;
    const int s0   = row0 & (S_ - 1);
    const int tid  = threadIdx.x;
    const int lane = tid & 63;
    const int wave = tid >> 6;
    const bf16_t* xzr = xz + (size_t)row0 * TWO_I;

    __shared__ float lnr[4][4][2];

    float xc[4][8];
    float sm[4] = {0.f, 0.f, 0.f, 0.f};
    float sq[4] = {0.f, 0.f, 0.f, 0.f};

    #pragma unroll
    for (int g = 0; g < 2; ++g) {
        const int c = g * 1024 + tid * 4;
        const f32x4 w0 = *(const f32x4*)(cwT + 0 * I_ + c);
        const f32x4 w1 = *(const f32x4*)(cwT + 1 * I_ + c);
        const f32x4 w2 = *(const f32x4*)(cwT + 2 * I_ + c);
        const f32x4 w3 = *(const f32x4*)(cwT + 3 * I_ + c);
        const f32x4 z4 = (f32x4){0.f, 0.f, 0.f, 0.f};
        f32x4 xv[7];
        #pragma unroll
        for (int j = 0; j < 7; ++j)
            xv[j] = (s0 + j >= 3)
                  ? b2f(*(const bf16x4*)(xzr + (ptrdiff_t)(j - 3) * TWO_I + c)) : z4;
        #pragma unroll
        for (int r = 0; r < 4; ++r) {
            const f32x4 a = w0 * xv[r] + w1 * xv[r + 1] + w2 * xv[r + 2] + w3 * xv[r + 3];
            #pragma unroll
            for (int e = 0; e < 4; ++e) {
                const float v = a[e];
                const float t = v * fast_sigmoid(v);
                xc[r][g * 4 + e] = t;
                sm[r] += t; sq[r] += t * t;
            }
        }
    }

    #pragma unroll
    for (int off = 32; off; off >>= 1)
        #pragma unroll
        for (int r = 0; r < 4; ++r) {
            sm[r] += __shfl_xor(sm[r], off, 64);
            sq[r] += __shfl_xor(sq[r], off, 64);
        }
    if (lane == 0)
        #pragma unroll
        for (int r = 0; r < 4; ++r) {
            lnr[wave][r][0] = sm[r]; lnr[wave][r][1] = sq[r];
        }
    __syncthreads();
    float mu[4], rs[4];
    #pragma unroll
    for (int r = 0; r < 4; ++r) {
        const float s  = lnr[0][r][0] + lnr[1][r][0] + lnr[2][r][0] + lnr[3][r][0];
        const float q  = lnr[0][r][1] + lnr[1][r][1] + lnr[2][r][1] + lnr[3][r][1];
        mu[r] = s * (1.f / I_);
        rs[r] = rsqrtf(q * (1.f / I_) - mu[r] * mu[r] + 1e-5f);
    }

    #pragma unroll
    for (int g = 0; g < 2; ++g) {
        const int c = g * 1024 + tid * 4;
        const f32x4 gg = *(const f32x4*)(ln_g + c);
        const f32x4 bb = *(const f32x4*)(ln_b + c);
        #pragma unroll
        for (int r = 0; r < 4; ++r) {
            bf16x4 h4;
            #pragma unroll
            for (int e = 0; e < 4; ++e)
                h4[e] = (bf16_t)((xc[r][g * 4 + e] - mu[r]) * rs[r] * gg[e] + bb[e]);
            *(bf16x4*)(Xn + (size_t)(row0 + r) * I_ + c) = h4;
        }
    }
}

// ---------------- xproj GEMM: xp_part[ks][ROWS][64] = Xn @ WxTb^T ----------------

__global__ __launch_bounds__(256)
void xproj_gemm(const bf16_t* __restrict__ Xn,
                const bf16_t* __restrict__ Wb, float* __restrict__ xp_part)
{
    constexpr int BM = 128, BK = 32, KS = 512;
    __shared__ bf16_t lA[BM * BK];
    __shared__ bf16_t lB[XPN * BK];

    const int bm   = blockIdx.x * BM;
    const int ks   = blockIdx.y;
    const int tid  = threadIdx.x;
    const int lane = tid & 63;
    const int wave = tid >> 6;
    const int wm   = (wave >> 1) * 64;
    const int wn   = (wave & 1) * 32;

    const int srow  = lane >> 2;
    const int skoff = (lane & 3) * 8;
    const int frow  = lane & 15;
    const int fko   = (lane >> 4) * 8;

    f32x4 acc[4][2];
    #pragma unroll
    for (int m = 0; m < 4; ++m)
        #pragma unroll
        for (int n = 0; n < 2; ++n)
            acc[m][n] = (f32x4){0.f, 0.f, 0.f, 0.f};

    for (int k0 = ks * KS; k0 < ks * KS + KS; k0 += BK) {
        #pragma unroll
        for (int t = 0; t < 2; ++t) {
            const int c = wave * 2 + t;
            const bf16_t* ga = Xn + (size_t)(bm + c * 16 + srow) * I_ + k0 + skoff;
            __builtin_amdgcn_global_load_lds(AS_G(ga), AS_L(lA + c * 512), 16, 0, 0);
        }
        const bf16_t* gb = Wb + (size_t)(wave * 16 + srow) * I_ + k0 + skoff;
        __builtin_amdgcn_global_load_lds(AS_G(gb), AS_L(lB + wave * 512), 16, 0, 0);
        __syncthreads();

        bf16x8 af[4], bf2[2];
        #pragma unroll
        for (int m = 0; m < 4; ++m)
            af[m] = *(const bf16x8*)(lA + (wm + m * 16 + frow) * BK + fko);
        #pragma unroll
        for (int n = 0; n < 2; ++n)
            bf2[n] = *(const bf16x8*)(lB + (wn + n * 16 + frow) * BK + fko);

        #pragma unroll
        for (int m = 0; m < 4; ++m)
            #pragma unroll
            for (int n = 0; n < 2; ++n)
                acc[m][n] = __builtin_amdgcn_mfma_f32_16x16x32_bf16(
                    af[m], bf2[n], acc[m][n], 0, 0, 0);

        __syncthreads();
    }

    float* out = xp_part + ((size_t)ks * ROWS + bm) * XPN;
    const int crow = (lane >> 4) * 4;
    const int ccol = lane & 15;
    #pragma unroll
    for (int m = 0; m < 4; ++m)
        #pragma unroll
        for (int n = 0; n < 2; ++n)
            #pragma unroll
            for (int r = 0; r < 4; ++r)
                out[(size_t)(wm + m * 16 + crow + r) * XPN
                    + (wn + n * 16 + ccol)] = acc[m][n][r];
}

// ---------------- SSM pointwise + gate -> U (bf16); 4 rows per block ----------------

__global__ __launch_bounds__(256)
void ssm_gate4(const bf16_t* __restrict__ xz,
               const bf16_t* __restrict__ Xn,
               const float* __restrict__ xp_part,  // [4][ROWS][64]
               const float* __restrict__ A2T,      // [16][I_]
               const float* __restrict__ Dv,       // [I_]
               bf16_t* __restrict__ U)             // [ROWS][I_]
{
    const int row0 = blockIdx.x * 4;
    const int tid  = threadIdx.x;

    __shared__ float xps[4][XPD];
    __shared__ float bcs[4][NST];

    if (tid < 4 * XPD) {
        const int r = tid / XPD;
        const int j = tid - r * XPD;
        float s = 0.f;
        #pragma unroll
        for (int ks = 0; ks < 4; ++ks)
            s += xp_part[((size_t)ks * ROWS + row0 + r) * XPN + j];
        xps[r][j] = s;
    }
    __syncthreads();
    if (tid < 4 * NST) {
        const int r = tid >> 4;
        const int n = tid & 15;
        bcs[r][n] = xps[r][1 + n] * xps[r][1 + NST + n];
    }
    __syncthreads();

    float d[4];
    #pragma unroll
    for (int r = 0; r < 4; ++r)
        d[r] = fminf(fmaxf(softplus_f(xps[r][0]), 1e-6f), 10.f);

    #pragma unroll 1
    for (int g = 0; g < 2; ++g) {
        const int c = g * 1024 + tid * 4;
        f32x4 sa[4];
        #pragma unroll
        for (int r = 0; r < 4; ++r)
            sa[r] = (f32x4){0.f, 0.f, 0.f, 0.f};

        #pragma unroll 1
        for (int nb = 0; nb < 4; ++nb) {
            const float* ap = A2T + (size_t)(nb * 4) * I_ + c;
            f32x4 av[4];
            #pragma unroll
            for (int j = 0; j < 4; ++j)
                av[j] = *(const f32x4*)(ap + (size_t)j * I_);
            #pragma unroll
            for (int j = 0; j < 4; ++j) {
                const float b0 = rflf(bcs[0][nb * 4 + j]);
                const float b1 = rflf(bcs[1][nb * 4 + j]);
                const float b2 = rflf(bcs[2][nb * 4 + j]);
                const float b3 = rflf(bcs[3][nb * 4 + j]);
                #pragma unroll
                for (int e = 0; e < 4; ++e) {
                    sa[0][e] += b0 * fast_exp2(d[0] * av[j][e]);
                    sa[1][e] += b1 * fast_exp2(d[1] * av[j][e]);
                    sa[2][e] += b2 * fast_exp2(d[2] * av[j][e]);
                    sa[3][e] += b3 * fast_exp2(d[3] * av[j][e]);
                }
            }
        }

        const f32x4 dvv = *(const f32x4*)(Dv + c);
        #pragma unroll
        for (int r = 0; r < 4; ++r) {
            const f32x4 xn = b2f(*(const bf16x4*)(Xn + (size_t)(row0 + r) * I_ + c));
            const f32x4 zv = b2f(*(const bf16x4*)(xz + (size_t)(row0 + r) * TWO_I + I_ + c));
            bf16x4 o;
            #pragma unroll
            for (int e = 0; e < 4; ++e) {
                const float y = xn[e] * (sa[r][e] + dvv[e]);
                const float z = zv[e];
                o[e] = (bf16_t)(y * z * fast_sigmoid(z));
            }
            *(bf16x4*)(U + (size_t)(row0 + r) * I_ + c) = o;
        }
    }
}

// ---------------- launch ----------------

extern "C" void kernel_launch(void* const* d_in, const int* in_sizes, int n_in,
                              void* d_out, int out_size, void* d_ws, size_t ws_size,
                              hipStream_t stream)
{
    const float* x     = (const float*)d_in[0];
    const float* W_in  = (const float*)d_in[1];
    const float* convw = (const float*)d_in[2];
    const float* ln_g  = (const float*)d_in[3];
    const float* ln_b  = (const float*)d_in[4];
    const float* Wx    = (const float*)d_in[5];
    const float* A_p   = (const float*)d_in[6];
    const float* Dv    = (const float*)d_in[7];
    const float* W_out = (const float*)d_in[8];
    float* out = (float*)d_out;

    char* ws = (char*)d_ws;
    bf16_t* Xb   = (bf16_t*)(ws);                                // 8 MiB (dead after GEMM1)
    bf16_t* W1t  = (bf16_t*)(ws + (size_t)(8u  << 20));          // 8 MiB (dead after GEMM1)
    bf16_t* Wot  = (bf16_t*)(ws + (size_t)(16u << 20));          // 4 MiB
    float*  A2T  = (float*) (ws + (size_t)(20u << 20));          // 128 KiB
    float*  cwT  = (float*) (ws + (size_t)(20u << 20) + (128u << 10)); // 32 KiB
    bf16_t* WxTb = (bf16_t*)(ws + (size_t)(20u << 20) + (256u << 10)); // 256 KiB
    bf16_t* XZb  = (bf16_t*)(ws + (size_t)(22u << 20));          // 32 MiB [4096][4096]
    bf16_t* U    = (bf16_t*)(ws + (size_t)(54u << 20));          // 16 MiB
    bf16_t* Xn   = (bf16_t*)(ws);                                // 16 MiB (reuses Xb+W1t)
    float*  xp4  = (float*) (ws + (size_t)(86u << 20));          // 4 MiB [4][4096][64]

    prep_all<<<10752, 256, 0, stream>>>(x, W_in, W_out, A_p, Wx, convw,
                                        Xb, W1t, Wot, A2T, cwT, WxTb);

    // GEMM1: R11 best — 256^2 tile, 8 waves, grid 256 (16x16, XCD 4x2 supertiles)
    gemm_fp<ROWS, TWO_I, H_, 256, 256, 2, 4, 512, 16, 16, 4, bf16_t>
        <<<256, 512, 0, stream>>>(Xb, W1t, XZb);
    conv_ln4<<<ROWS / 4, 256, 0, stream>>>(XZb, cwT, ln_g, ln_b, Xn);
    xproj_gemm<<<dim3(ROWS / 128, 4), 256, 0, stream>>>(Xn, WxTb, xp4);
    ssm_gate4<<<ROWS / 4, 256, 0, stream>>>(XZb, Xn, xp4, A2T, Dv, U);
    // GEMM3: 128^2 tile, 8 waves / 2 K-groups, grid 256 (8x32, XCD 2x4 supertiles)
    gemm3_kg<ROWS, H_, I_, 8, 32, 2>
        <<<256, 512, 0, stream>>>(U, Wot, out);
}